// Round 17
// baseline (1252.342 us; speedup 1.0000x reference)
//
#include <hip/hip_runtime.h>
#include <hip/hip_fp16.h>
#include <math.h>

#define NB 32
#define NL 512
#define NC 64
#define NG 3
#define NT 10000
#define NP 96
#define TOPM 20
#define M1 8      // per-lane per-chunk prefilter list
#define NCH 256   // t-chunks (250 real, 6 empty)
#define CHUNK 40
#define QK 16     // extracted per quarter (4 quarters -> 64 candidates)
#define NCAND 64
#define NENT (NB * NC * TOPM)  // 40960 selected entries
#define NROW (NB * NC)         // 2048 output rows
#define BINCAP 64
#define GSTRF ((size_t)NT * NC * 4)  // float stride between g-planes of ps

// ---------------------------------------------------------------------------
// Kernel 1: qstat (R5-R16-proven math). 32 blocks x 512 thr.
// ---------------------------------------------------------------------------
__global__ __launch_bounds__(512) void qstat_kernel(const float* __restrict__ x,
                                                    double* __restrict__ q) {
  __shared__ double s_sum[8][3][64], s_sq[8][3][64], s_abs[8][3][64];
  __shared__ double s_first[3][64], s_last[3][64];
  const int b = blockIdx.x, w = threadIdx.x >> 6, c = threadIdx.x & 63;
  const float* xp = x + (size_t)b * NL * NC + c;
  const int l0 = w * 64;
  double sum[3] = {0, 0, 0}, sumsq[3] = {0, 0, 0}, sumabs[3] = {0, 0, 0};
  double prev[3] = {0, 0, 0}, first[3] = {0, 0, 0};
  if (w > 0) {
    double e0 = xp[(l0 - 4) * NC], e1 = xp[(l0 - 3) * NC];
    double e2 = xp[(l0 - 2) * NC], e3 = xp[(l0 - 1) * NC];
    prev[2] = e3; prev[1] = (e2 + e3) * 0.5; prev[0] = (e0 + e1 + e2 + e3) * 0.25;
  }
  double acc2 = 0.0, acc4 = 0.0;
  for (int i = 0; i < 64; ++i) {
    const int l = l0 + i;
    double v = (double)xp[l * NC];
    sum[2] += v; sumsq[2] += v * v;
    if (l == 0) first[2] = v; else sumabs[2] += fabs(v - prev[2]);
    prev[2] = v;
    acc2 += v;
    if (l & 1) {
      double cur = acc2 * 0.5; acc2 = 0.0;
      sum[1] += cur; sumsq[1] += cur * cur;
      if (l == 1) first[1] = cur; else sumabs[1] += fabs(cur - prev[1]);
      prev[1] = cur;
    }
    acc4 += v;
    if ((l & 3) == 3) {
      double cur = acc4 * 0.25; acc4 = 0.0;
      sum[0] += cur; sumsq[0] += cur * cur;
      if (l == 3) first[0] = cur; else sumabs[0] += fabs(cur - prev[0]);
      prev[0] = cur;
    }
  }
  for (int g = 0; g < 3; ++g) {
    s_sum[w][g][c] = sum[g]; s_sq[w][g][c] = sumsq[g]; s_abs[w][g][c] = sumabs[g];
  }
  if (w == 0) { for (int g = 0; g < 3; ++g) s_first[g][c] = first[g]; }
  if (w == 7) { for (int g = 0; g < 3; ++g) s_last[g][c] = prev[g]; }
  __syncthreads();
  if (w == 0) {
    const double J[3] = {128.0, 256.0, 512.0};
    for (int g = 0; g < 3; ++g) {
      double S = 0, Q2 = 0, A = 0;
      for (int ww = 0; ww < 8; ++ww) {
        S += s_sum[ww][g][c]; Q2 += s_sq[ww][g][c]; A += s_abs[ww][g][c];
      }
      double mean = S / J[g];
      double var = Q2 / J[g] - mean * mean; if (var < 0.0) var = 0.0;
      double last = s_last[g][c];
      double s0 = mean - last;
      double s1 = sqrt(var);
      double s2 = (last - s_first[g][c]) * (1.0 / 511.0);
      double s3 = A * (1.0 / 511.0);
      double n = sqrt(s0 * s0 + s1 * s1 + s2 * s2 + s3 * s3);
      double inv = 1.0 / fmax(n, 1e-12);
      double* qp = q + ((((size_t)g * NB) + b) * NC + c) * 4;
      qp[0] = s0 * inv; qp[1] = s1 * inv; qp[2] = s2 * inv; qp[3] = s3 * inv;
    }
  }
}

// packed key: (ordermap16(fp16(v)) << 16) | (0xFFFF - t); u32-desc == (v desc, t asc)
__device__ __forceinline__ unsigned mkkey16(float v, int t) {
  unsigned h = (unsigned)__half_as_ushort(__float2half_rn(v));
  h = (h & 0x8000u) ? ((~h) & 0xFFFFu) : (h | 0x8000u);
  return (h << 16) | (0xFFFFu - (unsigned)t);
}

__device__ __forceinline__ void insert8k(unsigned k, unsigned key[M1]) {
  unsigned cv = k;
#pragma unroll
  for (int m = 0; m < M1; ++m) {
    bool sw = cv > key[m];
    unsigned tv = sw ? key[m] : cv;
    key[m] = sw ? cv : key[m];
    cv = tv;
  }
}

__device__ __forceinline__ float dot4f(float4 a, const float* qv) {
  return qv[0] * a.x + qv[1] * a.y + qv[2] * a.z + qv[3] * a.w;
}
__device__ __forceinline__ float nrm4f(float4 a) {
  float ss = a.x * a.x + a.y * a.y + a.z * a.z + a.w * a.w;
  return rsqrtf(fmaxf(ss, 1e-24f));
}

// ---------------------------------------------------------------------------
// Kernel 2 (R15/R16-proven): prefilter scan, inline fp32 norm from raw ps.
// 1024 thr = 16 b-waves sharing chunk stream; grid (2, NCH); LB(1024,8).
// Blocks (0, y<10) zero hist; block (1,0) zeros the row-completion counters.
// ---------------------------------------------------------------------------
__global__ __launch_bounds__(1024, 8) void sim32_kernel(
    const float* __restrict__ ps, const double* __restrict__ q,
    unsigned* __restrict__ ckey, int* __restrict__ hist, int* __restrict__ done) {
  if (blockIdx.x == 0 && blockIdx.y < 10) {
    const int idx = blockIdx.y * 1024 + threadIdx.x;
    if (idx < NT) hist[idx] = 0;
  }
  if (blockIdx.x == 1 && blockIdx.y == 0) {
    for (int j = threadIdx.x; j < NROW; j += 1024) done[j] = 0;
  }
  const int wav = threadIdx.x >> 6;
  const int c = threadIdx.x & 63;
  const int b = blockIdx.x * 16 + wav;
  const int ch = blockIdx.y;
  float qv[12];
#pragma unroll
  for (int g = 0; g < 3; ++g) {
    const double* qp = q + ((((size_t)g * NB) + b) * NC + c) * 4;
#pragma unroll
    for (int j = 0; j < 4; ++j) qv[g * 4 + j] = (float)(qp[j] * (1.0 / 3.0));
  }
  unsigned key[M1];
#pragma unroll
  for (int m = 0; m < M1; ++m) key[m] = 0u;
  int t0 = ch * CHUNK;
  int t1 = t0 + CHUNK; if (t1 > NT) t1 = NT;
  for (int t = t0; t + 1 < t1; t += 2) {
    const size_t oA = ((size_t)t * NC + c) * 4;
    const size_t oB = oA + (size_t)NC * 4;
    const float4 a0 = *reinterpret_cast<const float4*>(ps + oA);
    const float4 a1 = *reinterpret_cast<const float4*>(ps + GSTRF + oA);
    const float4 a2 = *reinterpret_cast<const float4*>(ps + 2 * GSTRF + oA);
    const float4 b0 = *reinterpret_cast<const float4*>(ps + oB);
    const float4 b1 = *reinterpret_cast<const float4*>(ps + GSTRF + oB);
    const float4 b2 = *reinterpret_cast<const float4*>(ps + 2 * GSTRF + oB);
    const float sA = dot4f(a0, qv) * nrm4f(a0) + dot4f(a1, qv + 4) * nrm4f(a1) +
                     dot4f(a2, qv + 8) * nrm4f(a2);
    const float sB = dot4f(b0, qv) * nrm4f(b0) + dot4f(b1, qv + 4) * nrm4f(b1) +
                     dot4f(b2, qv + 8) * nrm4f(b2);
    const unsigned kA = mkkey16(sA, t);
    const unsigned kB = mkkey16(sB, t + 1);
    if (kA > key[M1 - 1]) insert8k(kA, key);
    if (kB > key[M1 - 1]) insert8k(kB, key);
  }
  unsigned* ko = ckey + ((((size_t)b * NC) + c) * NCH + ch) * M1;
  *reinterpret_cast<uint4*>(ko) = make_uint4(key[0], key[1], key[2], key[3]);
  *reinterpret_cast<uint4*>(ko + 4) = make_uint4(key[4], key[5], key[6], key[7]);
}

// ---------------------------------------------------------------------------
// Kernel 3 (R14-R16-proven): merge + fp64 rerank (validated arithmetic) +
// softmax + direct fixed-capacity binning. Block = (c,b), 128 threads.
// ---------------------------------------------------------------------------
__global__ __launch_bounds__(128) void merge_rerank_kernel(
    const unsigned* __restrict__ ckey, const float* __restrict__ ps,
    const double* __restrict__ q, float* __restrict__ w_out,
    int* __restrict__ hist, int* __restrict__ bin_slot) {
  const int c = blockIdx.x, b = blockIdx.y;
  __shared__ unsigned k_s[NCH * M1];   // 8 KB
  __shared__ int ct_s[NCAND];
  __shared__ double rv_s[NCAND];
  __shared__ double m0_s, inv_s;
  __shared__ double e_s[TOPM];
  __shared__ int ts_s[TOPM];
  const int n = NCH * M1;  // 2048
  const size_t row = (size_t)b * NC + c;
  const uint4* kin = reinterpret_cast<const uint4*>(ckey + row * n);
  for (int k = threadIdx.x; k < n / 4; k += 128)
    *reinterpret_cast<uint4*>(&k_s[k * 4]) = kin[k];
  __syncthreads();
  // --- quarter extraction: quarter = (w<<1)|(lane>>5), 2 lists/lane ---
  {
    const int w = threadIdx.x >> 6, lane = threadIdx.x & 63;
    const int lane32 = lane & 31;
    const int qtr = (w << 1) | (lane >> 5);
    const int l0 = (qtr * 64 + lane32 * 2) * M1;
    const int l1 = l0 + M1;
    int p0 = 0, p1 = 0;
    unsigned k0 = k_s[l0], k1 = k_s[l1];
    for (int r = 0; r < QK; ++r) {
      const unsigned me = k0 > k1 ? k0 : k1;
      unsigned km = me;
#pragma unroll
      for (int st = 1; st < 32; st <<= 1) {
        const unsigned k2 = __shfl_xor(km, st);
        km = k2 > km ? k2 : km;
      }
      if (lane32 == r) ct_s[qtr * QK + r] = (int)(0xFFFFu - (km & 0xFFFFu));
      if (me == km) {  // unique keys -> exactly one owner
        if (k0 >= k1) { ++p0; k0 = (p0 < M1) ? k_s[l0 + p0] : 0u; }
        else          { ++p1; k1 = (p1 < M1) ? k_s[l1 + p1] : 0u; }
      }
    }
  }
  __syncthreads();
  // --- fp64 re-score of 64 candidates (identical arithmetic to validated) ---
  double myv = -1e300; int myt = 0x7fffffff;
  if (threadIdx.x < NCAND) {
    myt = ct_s[threadIdx.x];
    double s = 0.0;
#pragma unroll
    for (int g = 0; g < 3; ++g) {
      const double* qp = q + ((((size_t)g * NB) + b) * NC + c) * 4;
      const float4 pv = *reinterpret_cast<const float4*>(
          ps + ((((size_t)g * NT) + myt) * NC + c) * 4);
      double pp0 = pv.x, pp1 = pv.y, pp2 = pv.z, pp3 = pv.w;
      double ss = pp0 * pp0 + pp1 * pp1 + pp2 * pp2 + pp3 * pp3;
      double dot = qp[0] * pp0 + qp[1] * pp1 + qp[2] * pp2 + qp[3] * pp3;
      s += dot / fmax(sqrt(ss), 1e-12);
    }
    myv = s * (1.0 / 3.0);
    rv_s[threadIdx.x] = myv;
  }
  __syncthreads();
  // --- rank by counting (v desc, t asc); unique since t unique ---
  int rank = -1;
  if (threadIdx.x < NCAND) {
    rank = 0;
    for (int j = 0; j < NCAND; ++j) {
      double vj = rv_s[j]; int tj = ct_s[j];
      rank += (vj > myv) || (vj == myv && tj < myt);
    }
    if (rank == 0) m0_s = myv;
  }
  __syncthreads();
  if (rank >= 0 && rank < TOPM) { e_s[rank] = exp((myv - m0_s) * 10.0); ts_s[rank] = myt; }
  __syncthreads();
  if (threadIdx.x == 0) {
    double sum = 0.0;
#pragma unroll
    for (int m = 0; m < TOPM; ++m) sum += e_s[m];
    inv_s = 1.0 / sum;
  }
  __syncthreads();
  if (threadIdx.x < TOPM) {
    const int t = ts_s[threadIdx.x];
    const int i = (int)(row * TOPM) + threadIdx.x;
    w_out[i] = (float)(e_s[threadIdx.x] * inv_s);
    const int pos = atomicAdd(&hist[t], 1);
    if (pos < BINCAP) bin_slot[t * BINCAP + pos] = i;
  }
}

// ---------------------------------------------------------------------------
// Kernel 4 (fused finalize): one block per t, 512 thr. Stage y[t] (24KB
// contiguous) into LDS; serve k entries 4-way entry-parallel into fp16
// partials; then device-fence + per-row completion counter — the block
// performing a row's 20th increment reduces that row (fixed m-order, 96
// lanes) and writes out. Deterministic: sum order fixed, one writer per row.
// ---------------------------------------------------------------------------
__global__ __launch_bounds__(512) void process_kernel(
    const float* __restrict__ y, const int* __restrict__ hist,
    const int* __restrict__ bin_slot, const float* __restrict__ w_out,
    __half* __restrict__ partial, int* __restrict__ done,
    float* __restrict__ out) {
  const int t = blockIdx.x;
  int k = hist[t];
  if (k == 0) return;
  if (k > BINCAP) k = BINCAP;
  __shared__ float lds[NP * 65];   // 24,960 B
  __shared__ float w_l[BINCAP];
  __shared__ int i_l[BINCAP];
  __shared__ int c_l[BINCAP];
  __shared__ int rdone[BINCAP];
  const float4* yrow = reinterpret_cast<const float4*>(y + (size_t)t * NP * NC);
#pragma unroll
  for (int r = 0; r < 3; ++r) {
    const int e4 = threadIdx.x + r * 512;
    const float4 v = yrow[e4];
    const int p = e4 >> 4;
    const int c = (e4 & 15) * 4;
    lds[p * 65 + c] = v.x; lds[p * 65 + c + 1] = v.y;
    lds[p * 65 + c + 2] = v.z; lds[p * 65 + c + 3] = v.w;
  }
  if (threadIdx.x < k) {
    const int i = bin_slot[t * BINCAP + threadIdx.x];
    i_l[threadIdx.x] = i;
    w_l[threadIdx.x] = w_out[i];
    c_l[threadIdx.x] = (i / TOPM) & 63;
  }
  __syncthreads();
  {
    const int h = threadIdx.x >> 7;   // 4 entry-parallel quarters
    const int p = threadIdx.x & 127;
    for (int e = h; e < k; e += 4) {
      if (p < NP)
        partial[(size_t)i_l[e] * NP + p] =
            __float2half_rn(w_l[e] * lds[p * 65 + c_l[e]]);
    }
  }
  __threadfence();   // make this block's partials device-visible (G16)
  __syncthreads();
  // per-row completion: t's are unique within a row -> <=1 increment/block/row
  if (threadIdx.x < k) {
    const int row = i_l[threadIdx.x] / TOPM;
    rdone[threadIdx.x] = (atomicAdd(&done[row], 1) == TOPM - 1) ? row : -1;
  }
  __syncthreads();
  for (int e = 0; e < k; ++e) {
    const int row = rdone[e];
    if (row < 0) continue;
    const int p = threadIdx.x;
    if (p < NP) {
      const __half* pp = partial + (size_t)row * TOPM * NP + p;
      float acc = 0.f;
#pragma unroll
      for (int m = 0; m < TOPM; ++m) acc += __half2float(pp[m * NP]);
      out[((size_t)(row >> 6) * NP + p) * NC + (row & 63)] = acc;
    }
  }
}

// ---------------------------------------------------------------------------
// Fallback (small ws): round-1-proven all-fp64 inline path.
// ---------------------------------------------------------------------------
__global__ __launch_bounds__(256) void sim_topk_inline_kernel(
    const float* __restrict__ ps, const double* __restrict__ q,
    double* __restrict__ cval, int* __restrict__ cidx, int nch, int chunk) {
  const int wav = threadIdx.x >> 6;
  const int c = threadIdx.x & 63;
  const int b = blockIdx.y * 4 + wav;
  const int ch = blockIdx.x;
  double qv[3][4];
#pragma unroll
  for (int g = 0; g < 3; ++g) {
    const double* qp = q + ((((size_t)g * NB) + b) * NC + c) * 4;
    qv[g][0] = qp[0]; qv[g][1] = qp[1]; qv[g][2] = qp[2]; qv[g][3] = qp[3];
  }
  double val[TOPM]; int idx[TOPM];
#pragma unroll
  for (int m = 0; m < TOPM; ++m) { val[m] = -1e300; idx[m] = 0; }
  int t0 = ch * chunk;
  int t1 = t0 + chunk; if (t1 > NT) t1 = NT;
  for (int t = t0; t < t1; ++t) {
    double s = 0.0;
#pragma unroll
    for (int g = 0; g < 3; ++g) {
      const float4 pv = *reinterpret_cast<const float4*>(
          ps + ((((size_t)g * NT) + t) * NC + c) * 4);
      double p0 = pv.x, p1 = pv.y, p2 = pv.z, p3 = pv.w;
      double ss = p0 * p0 + p1 * p1 + p2 * p2 + p3 * p3;
      double dot = qv[g][0] * p0 + qv[g][1] * p1 + qv[g][2] * p2 + qv[g][3] * p3;
      s += dot / fmax(sqrt(ss), 1e-12);
    }
    s *= (1.0 / 3.0);
    if (s > val[TOPM - 1]) {
      double cv = s; int ci = t;
#pragma unroll
      for (int m = 0; m < TOPM; ++m) {
        bool sw = cv > val[m];
        double tv = sw ? val[m] : cv; int ti = sw ? idx[m] : ci;
        val[m] = sw ? cv : val[m];    idx[m] = sw ? ci : idx[m];
        cv = tv; ci = ti;
      }
    }
  }
  double* vout = cval + ((((size_t)b * NC) + c) * nch + ch) * TOPM;
  int* iout = cidx + ((((size_t)b * NC) + c) * nch + ch) * TOPM;
#pragma unroll
  for (int m = 0; m < TOPM; ++m) { vout[m] = val[m]; iout[m] = idx[m]; }
}

__global__ __launch_bounds__(128) void merge_gather_old_kernel(
    const double* __restrict__ cval, const int* __restrict__ cidx,
    const float* __restrict__ y, float* __restrict__ out, int nch) {
  const int c = blockIdx.x;
  const int b = blockIdx.y;
  __shared__ float w_s[TOPM];
  __shared__ int i_s[TOPM];
  if (threadIdx.x == 0) {
    double val[TOPM]; int idx[TOPM];
#pragma unroll
    for (int m = 0; m < TOPM; ++m) { val[m] = -1e300; idx[m] = 0; }
    const double* vin = cval + (((size_t)b * NC) + c) * nch * TOPM;
    const int* iin = cidx + (((size_t)b * NC) + c) * nch * TOPM;
    for (int k = 0; k < nch; ++k) {
      const int base = k * TOPM;
      for (int m = 0; m < TOPM; ++m) {
        double s = vin[base + m];
        if (!(s > val[TOPM - 1])) break;
        double cv = s; int ci = iin[base + m];
#pragma unroll
        for (int mm = 0; mm < TOPM; ++mm) {
          bool sw = cv > val[mm];
          double tv = sw ? val[mm] : cv; int ti = sw ? idx[mm] : ci;
          val[mm] = sw ? cv : val[mm];   idx[mm] = sw ? ci : idx[mm];
          cv = tv; ci = ti;
        }
      }
    }
    double mx = val[0];
    double e[TOPM]; double sum = 0.0;
#pragma unroll
    for (int m = 0; m < TOPM; ++m) { e[m] = exp((val[m] - mx) * 10.0); sum += e[m]; }
    double inv = 1.0 / sum;
#pragma unroll
    for (int m = 0; m < TOPM; ++m) { w_s[m] = (float)(e[m] * inv); i_s[m] = idx[m]; }
  }
  __syncthreads();
  const int p = threadIdx.x;
  if (p < NP) {
    float acc = 0.f;
#pragma unroll
    for (int m = 0; m < TOPM; ++m)
      acc += w_s[m] * y[(((size_t)i_s[m]) * NP + p) * NC + c];
    out[(((size_t)b * NP) + p) * NC + c] = acc;
  }
}

extern "C" void kernel_launch(void* const* d_in, const int* in_sizes, int n_in,
                              void* d_out, int out_size, void* d_ws, size_t ws_size,
                              hipStream_t stream) {
  const float* x = (const float*)d_in[0];
  const float* ps = (const float*)d_in[1];
  const float* y = (const float*)d_in[2];
  float* out = (float*)d_out;
  char* ws = (char*)d_ws;

  const size_t qbytes = (size_t)NG * NB * NC * 4 * sizeof(double);      // 196,608
  const size_t ckeybytes = (size_t)NB * NC * NCH * M1 * 4;              // 16.78 MB
  const size_t wtbytes = (size_t)NENT * 4;                              // 163,840
  const size_t histbytes = (size_t)NT * 4;                              // 40,000
  const size_t donebytes = (size_t)NROW * 4;                            // 8,192
  const size_t slotbytes = (size_t)NT * BINCAP * 4;                     // 2.56 MB
  const size_t partbytes = (size_t)NENT * NP * 2;                       // 7.86 MB

  double* qbuf = (double*)ws;
  size_t off = qbytes;
  unsigned* ckey = (unsigned*)(ws + off); off += ckeybytes;
  float* w_out = (float*)(ws + off); off += wtbytes;
  int* hist = (int*)(ws + off); off += histbytes;
  int* done = (int*)(ws + off); off += donebytes;
  off = (off + 7) & ~(size_t)7;
  int* bin_slot = (int*)(ws + off); off += slotbytes;
  __half* partial = (__half*)(ws + off); off += partbytes;

  if (ws_size >= off) {
    qstat_kernel<<<dim3(NB), dim3(512), 0, stream>>>(x, qbuf);
    sim32_kernel<<<dim3(NB / 16, NCH), dim3(1024), 0, stream>>>(ps, qbuf,
                                                                ckey, hist, done);
    merge_rerank_kernel<<<dim3(NC, NB), dim3(128), 0, stream>>>(
        ckey, ps, qbuf, w_out, hist, bin_slot);
    process_kernel<<<dim3(NT), dim3(512), 0, stream>>>(y, hist, bin_slot,
                                                       w_out, partial, done, out);
  } else {
    // fallback: round-1-proven all-fp64 path
    qstat_kernel<<<dim3(NB), dim3(512), 0, stream>>>(x, qbuf);
    const size_t per_ch = (size_t)NB * NC * TOPM * (sizeof(double) + sizeof(int));
    int nch = 1;
    if (ws_size > qbytes) {
      size_t mc = (ws_size - qbytes) / per_ch;
      nch = mc < 32 ? (int)mc : 32;
      if (nch < 1) nch = 1;
    }
    const int chunk = (NT + nch - 1) / nch;
    double* fcval = (double*)(ws + qbytes);
    int* fcidx = (int*)((char*)fcval + (size_t)NB * NC * nch * TOPM * sizeof(double));
    sim_topk_inline_kernel<<<dim3(nch, NB / 4), dim3(256), 0, stream>>>(
        ps, qbuf, fcval, fcidx, nch, chunk);
    merge_gather_old_kernel<<<dim3(NC, NB), dim3(128), 0, stream>>>(fcval, fcidx, y,
                                                                    out, nch);
  }
}

// Round 18
// 116.238 us; speedup vs baseline: 10.7740x; 10.7740x over previous
//
#include <hip/hip_runtime.h>
#include <hip/hip_fp16.h>
#include <math.h>

#define NB 32
#define NL 512
#define NC 64
#define NG 3
#define NT 10000
#define NP 96
#define TOPM 20
#define M1 8      // per-lane per-chunk prefilter list
#define NCH 256   // t-chunks (250 real, 6 empty)
#define CHUNK 40
#define QK 16     // extracted per quarter (4 quarters -> 64 candidates)
#define NCAND 64
#define NENT (NB * NC * TOPM)  // 40960 selected entries
#define BINCAP 64
#define GSTRF ((size_t)NT * NC * 4)  // float stride between g-planes of ps

// ---------------------------------------------------------------------------
// Kernel 1: qstat (R5-R16-proven math). 32 blocks x 512 thr.
// ---------------------------------------------------------------------------
__global__ __launch_bounds__(512) void qstat_kernel(const float* __restrict__ x,
                                                    double* __restrict__ q) {
  __shared__ double s_sum[8][3][64], s_sq[8][3][64], s_abs[8][3][64];
  __shared__ double s_first[3][64], s_last[3][64];
  const int b = blockIdx.x, w = threadIdx.x >> 6, c = threadIdx.x & 63;
  const float* xp = x + (size_t)b * NL * NC + c;
  const int l0 = w * 64;
  double sum[3] = {0, 0, 0}, sumsq[3] = {0, 0, 0}, sumabs[3] = {0, 0, 0};
  double prev[3] = {0, 0, 0}, first[3] = {0, 0, 0};
  if (w > 0) {
    double e0 = xp[(l0 - 4) * NC], e1 = xp[(l0 - 3) * NC];
    double e2 = xp[(l0 - 2) * NC], e3 = xp[(l0 - 1) * NC];
    prev[2] = e3; prev[1] = (e2 + e3) * 0.5; prev[0] = (e0 + e1 + e2 + e3) * 0.25;
  }
  double acc2 = 0.0, acc4 = 0.0;
  for (int i = 0; i < 64; ++i) {
    const int l = l0 + i;
    double v = (double)xp[l * NC];
    sum[2] += v; sumsq[2] += v * v;
    if (l == 0) first[2] = v; else sumabs[2] += fabs(v - prev[2]);
    prev[2] = v;
    acc2 += v;
    if (l & 1) {
      double cur = acc2 * 0.5; acc2 = 0.0;
      sum[1] += cur; sumsq[1] += cur * cur;
      if (l == 1) first[1] = cur; else sumabs[1] += fabs(cur - prev[1]);
      prev[1] = cur;
    }
    acc4 += v;
    if ((l & 3) == 3) {
      double cur = acc4 * 0.25; acc4 = 0.0;
      sum[0] += cur; sumsq[0] += cur * cur;
      if (l == 3) first[0] = cur; else sumabs[0] += fabs(cur - prev[0]);
      prev[0] = cur;
    }
  }
  for (int g = 0; g < 3; ++g) {
    s_sum[w][g][c] = sum[g]; s_sq[w][g][c] = sumsq[g]; s_abs[w][g][c] = sumabs[g];
  }
  if (w == 0) { for (int g = 0; g < 3; ++g) s_first[g][c] = first[g]; }
  if (w == 7) { for (int g = 0; g < 3; ++g) s_last[g][c] = prev[g]; }
  __syncthreads();
  if (w == 0) {
    const double J[3] = {128.0, 256.0, 512.0};
    for (int g = 0; g < 3; ++g) {
      double S = 0, Q2 = 0, A = 0;
      for (int ww = 0; ww < 8; ++ww) {
        S += s_sum[ww][g][c]; Q2 += s_sq[ww][g][c]; A += s_abs[ww][g][c];
      }
      double mean = S / J[g];
      double var = Q2 / J[g] - mean * mean; if (var < 0.0) var = 0.0;
      double last = s_last[g][c];
      double s0 = mean - last;
      double s1 = sqrt(var);
      double s2 = (last - s_first[g][c]) * (1.0 / 511.0);
      double s3 = A * (1.0 / 511.0);
      double n = sqrt(s0 * s0 + s1 * s1 + s2 * s2 + s3 * s3);
      double inv = 1.0 / fmax(n, 1e-12);
      double* qp = q + ((((size_t)g * NB) + b) * NC + c) * 4;
      qp[0] = s0 * inv; qp[1] = s1 * inv; qp[2] = s2 * inv; qp[3] = s3 * inv;
    }
  }
}

// packed key: (ordermap16(fp16(v)) << 16) | (0xFFFF - t); u32-desc == (v desc, t asc)
__device__ __forceinline__ unsigned mkkey16(float v, int t) {
  unsigned h = (unsigned)__half_as_ushort(__float2half_rn(v));
  h = (h & 0x8000u) ? ((~h) & 0xFFFFu) : (h | 0x8000u);
  return (h << 16) | (0xFFFFu - (unsigned)t);
}

__device__ __forceinline__ void insert8k(unsigned k, unsigned key[M1]) {
  unsigned cv = k;
#pragma unroll
  for (int m = 0; m < M1; ++m) {
    bool sw = cv > key[m];
    unsigned tv = sw ? key[m] : cv;
    key[m] = sw ? cv : key[m];
    cv = tv;
  }
}

__device__ __forceinline__ float dot4f(float4 a, const float* qv) {
  return qv[0] * a.x + qv[1] * a.y + qv[2] * a.z + qv[3] * a.w;
}
__device__ __forceinline__ float nrm4f(float4 a) {
  float ss = a.x * a.x + a.y * a.y + a.z * a.z + a.w * a.w;
  return rsqrtf(fmaxf(ss, 1e-24f));
}

// ---------------------------------------------------------------------------
// Kernel 2 (R15/R16-proven): prefilter scan, inline fp32 norm from raw ps.
// 1024 thr = 16 b-waves sharing chunk stream; grid (2, NCH); LB(1024,8).
// Blocks (0, y<10) zero the t-histogram.
// ---------------------------------------------------------------------------
__global__ __launch_bounds__(1024, 8) void sim32_kernel(
    const float* __restrict__ ps, const double* __restrict__ q,
    unsigned* __restrict__ ckey, int* __restrict__ hist) {
  if (blockIdx.x == 0 && blockIdx.y < 10) {
    const int idx = blockIdx.y * 1024 + threadIdx.x;
    if (idx < NT) hist[idx] = 0;
  }
  const int wav = threadIdx.x >> 6;
  const int c = threadIdx.x & 63;
  const int b = blockIdx.x * 16 + wav;
  const int ch = blockIdx.y;
  float qv[12];
#pragma unroll
  for (int g = 0; g < 3; ++g) {
    const double* qp = q + ((((size_t)g * NB) + b) * NC + c) * 4;
#pragma unroll
    for (int j = 0; j < 4; ++j) qv[g * 4 + j] = (float)(qp[j] * (1.0 / 3.0));
  }
  unsigned key[M1];
#pragma unroll
  for (int m = 0; m < M1; ++m) key[m] = 0u;
  int t0 = ch * CHUNK;
  int t1 = t0 + CHUNK; if (t1 > NT) t1 = NT;
  for (int t = t0; t + 1 < t1; t += 2) {
    const size_t oA = ((size_t)t * NC + c) * 4;
    const size_t oB = oA + (size_t)NC * 4;
    const float4 a0 = *reinterpret_cast<const float4*>(ps + oA);
    const float4 a1 = *reinterpret_cast<const float4*>(ps + GSTRF + oA);
    const float4 a2 = *reinterpret_cast<const float4*>(ps + 2 * GSTRF + oA);
    const float4 b0 = *reinterpret_cast<const float4*>(ps + oB);
    const float4 b1 = *reinterpret_cast<const float4*>(ps + GSTRF + oB);
    const float4 b2 = *reinterpret_cast<const float4*>(ps + 2 * GSTRF + oB);
    const float sA = dot4f(a0, qv) * nrm4f(a0) + dot4f(a1, qv + 4) * nrm4f(a1) +
                     dot4f(a2, qv + 8) * nrm4f(a2);
    const float sB = dot4f(b0, qv) * nrm4f(b0) + dot4f(b1, qv + 4) * nrm4f(b1) +
                     dot4f(b2, qv + 8) * nrm4f(b2);
    const unsigned kA = mkkey16(sA, t);
    const unsigned kB = mkkey16(sB, t + 1);
    if (kA > key[M1 - 1]) insert8k(kA, key);
    if (kB > key[M1 - 1]) insert8k(kB, key);
  }
  unsigned* ko = ckey + ((((size_t)b * NC) + c) * NCH + ch) * M1;
  *reinterpret_cast<uint4*>(ko) = make_uint4(key[0], key[1], key[2], key[3]);
  *reinterpret_cast<uint4*>(ko + 4) = make_uint4(key[4], key[5], key[6], key[7]);
}

// ---------------------------------------------------------------------------
// Kernel 3 (R14-R16-proven): merge + fp64 rerank (validated arithmetic) +
// softmax + direct fixed-capacity binning. Block = (c,b), 128 threads.
// ---------------------------------------------------------------------------
__global__ __launch_bounds__(128) void merge_rerank_kernel(
    const unsigned* __restrict__ ckey, const float* __restrict__ ps,
    const double* __restrict__ q, float* __restrict__ w_out,
    int* __restrict__ hist, int* __restrict__ bin_slot) {
  const int c = blockIdx.x, b = blockIdx.y;
  __shared__ unsigned k_s[NCH * M1];   // 8 KB
  __shared__ int ct_s[NCAND];
  __shared__ double rv_s[NCAND];
  __shared__ double m0_s, inv_s;
  __shared__ double e_s[TOPM];
  __shared__ int ts_s[TOPM];
  const int n = NCH * M1;  // 2048
  const size_t row = (size_t)b * NC + c;
  const uint4* kin = reinterpret_cast<const uint4*>(ckey + row * n);
  for (int k = threadIdx.x; k < n / 4; k += 128)
    *reinterpret_cast<uint4*>(&k_s[k * 4]) = kin[k];
  __syncthreads();
  // --- quarter extraction: quarter = (w<<1)|(lane>>5), 2 lists/lane ---
  {
    const int w = threadIdx.x >> 6, lane = threadIdx.x & 63;
    const int lane32 = lane & 31;
    const int qtr = (w << 1) | (lane >> 5);
    const int l0 = (qtr * 64 + lane32 * 2) * M1;
    const int l1 = l0 + M1;
    int p0 = 0, p1 = 0;
    unsigned k0 = k_s[l0], k1 = k_s[l1];
    for (int r = 0; r < QK; ++r) {
      const unsigned me = k0 > k1 ? k0 : k1;
      unsigned km = me;
#pragma unroll
      for (int st = 1; st < 32; st <<= 1) {
        const unsigned k2 = __shfl_xor(km, st);
        km = k2 > km ? k2 : km;
      }
      if (lane32 == r) ct_s[qtr * QK + r] = (int)(0xFFFFu - (km & 0xFFFFu));
      if (me == km) {  // unique keys -> exactly one owner
        if (k0 >= k1) { ++p0; k0 = (p0 < M1) ? k_s[l0 + p0] : 0u; }
        else          { ++p1; k1 = (p1 < M1) ? k_s[l1 + p1] : 0u; }
      }
    }
  }
  __syncthreads();
  // --- fp64 re-score of 64 candidates (identical arithmetic to validated) ---
  double myv = -1e300; int myt = 0x7fffffff;
  if (threadIdx.x < NCAND) {
    myt = ct_s[threadIdx.x];
    double s = 0.0;
#pragma unroll
    for (int g = 0; g < 3; ++g) {
      const double* qp = q + ((((size_t)g * NB) + b) * NC + c) * 4;
      const float4 pv = *reinterpret_cast<const float4*>(
          ps + ((((size_t)g * NT) + myt) * NC + c) * 4);
      double pp0 = pv.x, pp1 = pv.y, pp2 = pv.z, pp3 = pv.w;
      double ss = pp0 * pp0 + pp1 * pp1 + pp2 * pp2 + pp3 * pp3;
      double dot = qp[0] * pp0 + qp[1] * pp1 + qp[2] * pp2 + qp[3] * pp3;
      s += dot / fmax(sqrt(ss), 1e-12);
    }
    myv = s * (1.0 / 3.0);
    rv_s[threadIdx.x] = myv;
  }
  __syncthreads();
  // --- rank by counting (v desc, t asc); unique since t unique ---
  int rank = -1;
  if (threadIdx.x < NCAND) {
    rank = 0;
    for (int j = 0; j < NCAND; ++j) {
      double vj = rv_s[j]; int tj = ct_s[j];
      rank += (vj > myv) || (vj == myv && tj < myt);
    }
    if (rank == 0) m0_s = myv;
  }
  __syncthreads();
  if (rank >= 0 && rank < TOPM) { e_s[rank] = exp((myv - m0_s) * 10.0); ts_s[rank] = myt; }
  __syncthreads();
  if (threadIdx.x == 0) {
    double sum = 0.0;
#pragma unroll
    for (int m = 0; m < TOPM; ++m) sum += e_s[m];
    inv_s = 1.0 / sum;
  }
  __syncthreads();
  if (threadIdx.x < TOPM) {
    const int t = ts_s[threadIdx.x];
    const int i = (int)(row * TOPM) + threadIdx.x;
    w_out[i] = (float)(e_s[threadIdx.x] * inv_s);
    const int pos = atomicAdd(&hist[t], 1);
    if (pos < BINCAP) bin_slot[t * BINCAP + pos] = i;
  }
}

// ---------------------------------------------------------------------------
// Kernel 4 (R16-proven): one block per t, 512 thr. Stage y[t] (24KB
// contiguous) into LDS (65-float stride, 2-way banks = free); serve k entries
// 4-way entry-parallel. partial16[i][p] = fp16(w_i * y[t][p][c_i]).
// ---------------------------------------------------------------------------
__global__ __launch_bounds__(512) void process_kernel(
    const float* __restrict__ y, const int* __restrict__ hist,
    const int* __restrict__ bin_slot, const float* __restrict__ w_out,
    __half* __restrict__ partial) {
  const int t = blockIdx.x;
  int k = hist[t];
  if (k == 0) return;
  if (k > BINCAP) k = BINCAP;
  __shared__ float lds[NP * 65];   // 24,960 B
  __shared__ float w_l[BINCAP];
  __shared__ int i_l[BINCAP];
  __shared__ int c_l[BINCAP];
  const float4* yrow = reinterpret_cast<const float4*>(y + (size_t)t * NP * NC);
#pragma unroll
  for (int r = 0; r < 3; ++r) {
    const int e4 = threadIdx.x + r * 512;
    const float4 v = yrow[e4];
    const int p = e4 >> 4;
    const int c = (e4 & 15) * 4;
    lds[p * 65 + c] = v.x; lds[p * 65 + c + 1] = v.y;
    lds[p * 65 + c + 2] = v.z; lds[p * 65 + c + 3] = v.w;
  }
  if (threadIdx.x < k) {
    const int i = bin_slot[t * BINCAP + threadIdx.x];
    i_l[threadIdx.x] = i;
    w_l[threadIdx.x] = w_out[i];
    c_l[threadIdx.x] = (i / TOPM) & 63;
  }
  __syncthreads();
  const int h = threadIdx.x >> 7;   // 4 entry-parallel quarters
  const int p = threadIdx.x & 127;
  for (int e = h; e < k; e += 4) {
    if (p < NP)
      partial[(size_t)i_l[e] * NP + p] =
          __float2half_rn(w_l[e] * lds[p * 65 + c_l[e]]);
  }
}

// ---------------------------------------------------------------------------
// Kernel 5 (R16-proven): out[b][p][c] = sum_m fp32(partial16[row*20+m][p]).
// ---------------------------------------------------------------------------
__global__ __launch_bounds__(128) void final_kernel(const __half* __restrict__ partial,
                                                    float* __restrict__ out) {
  const int row = blockIdx.x;
  const int p = threadIdx.x;
  if (p >= NP) return;
  const int b = row >> 6, c = row & 63;
  const __half* pp = partial + (size_t)row * TOPM * NP + p;
  float acc = 0.f;
#pragma unroll
  for (int m = 0; m < TOPM; ++m) acc += __half2float(pp[m * NP]);
  out[(((size_t)b * NP) + p) * NC + c] = acc;
}

// ---------------------------------------------------------------------------
// Fallback (small ws): round-1-proven all-fp64 inline path.
// ---------------------------------------------------------------------------
__global__ __launch_bounds__(256) void sim_topk_inline_kernel(
    const float* __restrict__ ps, const double* __restrict__ q,
    double* __restrict__ cval, int* __restrict__ cidx, int nch, int chunk) {
  const int wav = threadIdx.x >> 6;
  const int c = threadIdx.x & 63;
  const int b = blockIdx.y * 4 + wav;
  const int ch = blockIdx.x;
  double qv[3][4];
#pragma unroll
  for (int g = 0; g < 3; ++g) {
    const double* qp = q + ((((size_t)g * NB) + b) * NC + c) * 4;
    qv[g][0] = qp[0]; qv[g][1] = qp[1]; qv[g][2] = qp[2]; qv[g][3] = qp[3];
  }
  double val[TOPM]; int idx[TOPM];
#pragma unroll
  for (int m = 0; m < TOPM; ++m) { val[m] = -1e300; idx[m] = 0; }
  int t0 = ch * chunk;
  int t1 = t0 + chunk; if (t1 > NT) t1 = NT;
  for (int t = t0; t < t1; ++t) {
    double s = 0.0;
#pragma unroll
    for (int g = 0; g < 3; ++g) {
      const float4 pv = *reinterpret_cast<const float4*>(
          ps + ((((size_t)g * NT) + t) * NC + c) * 4);
      double p0 = pv.x, p1 = pv.y, p2 = pv.z, p3 = pv.w;
      double ss = p0 * p0 + p1 * p1 + p2 * p2 + p3 * p3;
      double dot = qv[g][0] * p0 + qv[g][1] * p1 + qv[g][2] * p2 + qv[g][3] * p3;
      s += dot / fmax(sqrt(ss), 1e-12);
    }
    s *= (1.0 / 3.0);
    if (s > val[TOPM - 1]) {
      double cv = s; int ci = t;
#pragma unroll
      for (int m = 0; m < TOPM; ++m) {
        bool sw = cv > val[m];
        double tv = sw ? val[m] : cv; int ti = sw ? idx[m] : ci;
        val[m] = sw ? cv : val[m];    idx[m] = sw ? ci : idx[m];
        cv = tv; ci = ti;
      }
    }
  }
  double* vout = cval + ((((size_t)b * NC) + c) * nch + ch) * TOPM;
  int* iout = cidx + ((((size_t)b * NC) + c) * nch + ch) * TOPM;
#pragma unroll
  for (int m = 0; m < TOPM; ++m) { vout[m] = val[m]; iout[m] = idx[m]; }
}

__global__ __launch_bounds__(128) void merge_gather_old_kernel(
    const double* __restrict__ cval, const int* __restrict__ cidx,
    const float* __restrict__ y, float* __restrict__ out, int nch) {
  const int c = blockIdx.x;
  const int b = blockIdx.y;
  __shared__ float w_s[TOPM];
  __shared__ int i_s[TOPM];
  if (threadIdx.x == 0) {
    double val[TOPM]; int idx[TOPM];
#pragma unroll
    for (int m = 0; m < TOPM; ++m) { val[m] = -1e300; idx[m] = 0; }
    const double* vin = cval + (((size_t)b * NC) + c) * nch * TOPM;
    const int* iin = cidx + (((size_t)b * NC) + c) * nch * TOPM;
    for (int k = 0; k < nch; ++k) {
      const int base = k * TOPM;
      for (int m = 0; m < TOPM; ++m) {
        double s = vin[base + m];
        if (!(s > val[TOPM - 1])) break;
        double cv = s; int ci = iin[base + m];
#pragma unroll
        for (int mm = 0; mm < TOPM; ++mm) {
          bool sw = cv > val[mm];
          double tv = sw ? val[mm] : cv; int ti = sw ? idx[mm] : ci;
          val[mm] = sw ? cv : val[mm];   idx[mm] = sw ? ci : idx[mm];
          cv = tv; ci = ti;
        }
      }
    }
    double mx = val[0];
    double e[TOPM]; double sum = 0.0;
#pragma unroll
    for (int m = 0; m < TOPM; ++m) { e[m] = exp((val[m] - mx) * 10.0); sum += e[m]; }
    double inv = 1.0 / sum;
#pragma unroll
    for (int m = 0; m < TOPM; ++m) { w_s[m] = (float)(e[m] * inv); i_s[m] = idx[m]; }
  }
  __syncthreads();
  const int p = threadIdx.x;
  if (p < NP) {
    float acc = 0.f;
#pragma unroll
    for (int m = 0; m < TOPM; ++m)
      acc += w_s[m] * y[(((size_t)i_s[m]) * NP + p) * NC + c];
    out[(((size_t)b * NP) + p) * NC + c] = acc;
  }
}

extern "C" void kernel_launch(void* const* d_in, const int* in_sizes, int n_in,
                              void* d_out, int out_size, void* d_ws, size_t ws_size,
                              hipStream_t stream) {
  const float* x = (const float*)d_in[0];
  const float* ps = (const float*)d_in[1];
  const float* y = (const float*)d_in[2];
  float* out = (float*)d_out;
  char* ws = (char*)d_ws;

  const size_t qbytes = (size_t)NG * NB * NC * 4 * sizeof(double);      // 196,608
  const size_t ckeybytes = (size_t)NB * NC * NCH * M1 * 4;              // 16.78 MB
  const size_t wtbytes = (size_t)NENT * 4;                              // 163,840
  const size_t histbytes = (size_t)NT * 4;                              // 40,000
  const size_t slotbytes = (size_t)NT * BINCAP * 4;                     // 2.56 MB
  const size_t partbytes = (size_t)NENT * NP * 2;                       // 7.86 MB

  double* qbuf = (double*)ws;
  size_t off = qbytes;
  unsigned* ckey = (unsigned*)(ws + off); off += ckeybytes;
  float* w_out = (float*)(ws + off); off += wtbytes;
  int* hist = (int*)(ws + off); off += histbytes;
  off = (off + 7) & ~(size_t)7;
  int* bin_slot = (int*)(ws + off); off += slotbytes;
  __half* partial = (__half*)(ws + off); off += partbytes;

  if (ws_size >= off) {
    qstat_kernel<<<dim3(NB), dim3(512), 0, stream>>>(x, qbuf);
    sim32_kernel<<<dim3(NB / 16, NCH), dim3(1024), 0, stream>>>(ps, qbuf,
                                                                ckey, hist);
    merge_rerank_kernel<<<dim3(NC, NB), dim3(128), 0, stream>>>(
        ckey, ps, qbuf, w_out, hist, bin_slot);
    process_kernel<<<dim3(NT), dim3(512), 0, stream>>>(y, hist, bin_slot,
                                                       w_out, partial);
    final_kernel<<<dim3(NB * NC), dim3(128), 0, stream>>>(partial, out);
  } else {
    // fallback: round-1-proven all-fp64 path
    qstat_kernel<<<dim3(NB), dim3(512), 0, stream>>>(x, qbuf);
    const size_t per_ch = (size_t)NB * NC * TOPM * (sizeof(double) + sizeof(int));
    int nch = 1;
    if (ws_size > qbytes) {
      size_t mc = (ws_size - qbytes) / per_ch;
      nch = mc < 32 ? (int)mc : 32;
      if (nch < 1) nch = 1;
    }
    const int chunk = (NT + nch - 1) / nch;
    double* fcval = (double*)(ws + qbytes);
    int* fcidx = (int*)((char*)fcval + (size_t)NB * NC * nch * TOPM * sizeof(double));
    sim_topk_inline_kernel<<<dim3(nch, NB / 4), dim3(256), 0, stream>>>(
        ps, qbuf, fcval, fcidx, nch, chunk);
    merge_gather_old_kernel<<<dim3(NC, NB), dim3(128), 0, stream>>>(fcval, fcidx, y,
                                                                    out, nch);
  }
}